// Round 1
// baseline (321.579 us; speedup 1.0000x reference)
//
#include <hip/hip_runtime.h>
#include <hip/hip_bf16.h>

// Problem constants (from reference): B=2, S=2048 -> T=4096 tokens
#define T_TOK 4096
#define DDIM  1024
#define FDIM  512
#define NEXP  16
#define NE17  17   // 16 experts + shared expert as expert 16 (cw=1)

using bf16x8 = __attribute__((ext_vector_type(8))) __bf16;
using f32x4  = __attribute__((ext_vector_type(4))) float;

// ---------------------------------------------------------------------------
// async global->LDS, 16B per lane. LDS dest = wave-uniform base + lane*16.
__device__ __forceinline__ void gload_lds16(const void* g, void* l) {
  __builtin_amdgcn_global_load_lds(
      (const __attribute__((address_space(1))) void*)g,
      (__attribute__((address_space(3))) void*)l, 16, 0, 0);
}

// XOR-swizzled ds_read_b128 of one MFMA fragment (8 bf16 along K).
// All LDS tiles are [rows][64] bf16 => 128B rows. chunk = 16B unit along K.
__device__ __forceinline__ bf16x8 frag_ld(const __hip_bfloat16* smem, int row, int chunk) {
  const char* p = (const char*)smem + row * 128 + ((chunk ^ (row & 7)) << 4);
  return *(const bf16x8*)p;
}

// ---------------------------------------------------------------------------
// Router: logits = x @ rw^T, softmax, top-8, renormalize -> cw[T][16] fp32
__global__ void moe_router(const float* __restrict__ x, const float* __restrict__ rw,
                           float* __restrict__ cw) {
  const int t = blockIdx.x;
  const int lane = threadIdx.x;  // 64 threads
  float xr[16];
#pragma unroll
  for (int j = 0; j < 16; j++) xr[j] = x[(size_t)t * DDIM + lane + 64 * j];
  float lg[16];
#pragma unroll
  for (int e = 0; e < 16; e++) {
    const float* r = rw + (size_t)e * DDIM;
    float p = 0.f;
#pragma unroll
    for (int j = 0; j < 16; j++) p += xr[j] * r[lane + 64 * j];
#pragma unroll
    for (int off = 32; off > 0; off >>= 1) p += __shfl_xor(p, off);
    lg[e] = p;
  }
  if (lane == 0) {
    float m = lg[0];
    for (int e = 1; e < 16; e++) m = fmaxf(m, lg[e]);
    float pr[16];
    for (int e = 0; e < 16; e++) pr[e] = __expf(lg[e] - m);
    unsigned sel = 0;
    for (int it = 0; it < 8; it++) {  // top-8 by prob (== top-8 by logit)
      int bi = 0; float bv = -1.f;
      for (int e2 = 0; e2 < 16; e2++)
        if (!((sel >> e2) & 1) && pr[e2] > bv) { bv = pr[e2]; bi = e2; }
      sel |= 1u << bi;
    }
    float s = 0.f;
    for (int e = 0; e < 16; e++) if ((sel >> e) & 1) s += pr[e];
    const float inv = 1.0f / s;
    for (int e = 0; e < 16; e++)
      cw[(size_t)t * 16 + e] = ((sel >> e) & 1) ? pr[e] * inv : 0.f;
  }
}

// ---------------------------------------------------------------------------
// fp32 -> bf16 elementwise (4 elems/thread)
__global__ void convert_bf16(const float* __restrict__ in, __hip_bfloat16* __restrict__ out,
                             int n4) {
  int i = blockIdx.x * blockDim.x + threadIdx.x;
  if (i >= n4) return;
  float4 v = ((const float4*)in)[i];
  __hip_bfloat16 h[4] = {__float2bfloat16(v.x), __float2bfloat16(v.y),
                         __float2bfloat16(v.z), __float2bfloat16(v.w)};
  *(uint2*)(out + (size_t)i * 4) = *(const uint2*)h;
}

// Transpose-convert: in [R][C] fp32 (expert e<16 from srcMain, e==16 from srcShared)
// -> out [C][R] bf16 at dst + e*R*C
__global__ void transpose_convert(const float* __restrict__ srcMain,
                                  const float* __restrict__ srcShared,
                                  __hip_bfloat16* __restrict__ dst, int R, int C) {
  const int e = blockIdx.z;
  const float* src = (e < NEXP) ? srcMain + (size_t)e * R * C : srcShared;
  __hip_bfloat16* out = dst + (size_t)e * R * C;
  __shared__ float tile[32][33];
  const int c0 = blockIdx.x * 32, r0 = blockIdx.y * 32;
  const int tx = threadIdx.x, ty = threadIdx.y;  // 32 x 8
#pragma unroll
  for (int i = 0; i < 32; i += 8)
    tile[ty + i][tx] = src[(size_t)(r0 + ty + i) * C + c0 + tx];
  __syncthreads();
#pragma unroll
  for (int i = 0; i < 32; i += 8)
    out[(size_t)(c0 + ty + i) * R + r0 + tx] = __float2bfloat16(tile[tx][ty + i]);
}

// ---------------------------------------------------------------------------
// Stage A: per (expert e, 128 tokens, 128 f-cols):
//   G = X @ Wg[e], U = X @ Wu[e]  (dual accumulate, shared X tile)
//   H[e][t][f] = silu(G)*U * cw[t][e]   (e==16 -> shared expert, cw=1)
// Wg/Wu pre-transposed to [17][F][D] so both operands are K(=D)-contiguous.
__global__ __launch_bounds__(256, 2) void moe_stageA(
    const __hip_bfloat16* __restrict__ xb,   // [T][D]
    const __hip_bfloat16* __restrict__ wg,   // [17][F][D]
    const __hip_bfloat16* __restrict__ wu,   // [17][F][D]
    const float* __restrict__ cw,            // [T][16]
    __hip_bfloat16* __restrict__ H)          // [17][T][F]
{
  __shared__ __hip_bfloat16 sA[128 * 64];
  __shared__ __hip_bfloat16 sG[128 * 64];
  __shared__ __hip_bfloat16 sU[128 * 64];
  __shared__ float scw[128];

  const int e  = blockIdx.z;
  const int t0 = blockIdx.x * 128;
  const int f0 = blockIdx.y * 128;
  const int tid = threadIdx.x;
  const int wid = tid >> 6, lane = tid & 63;
  const int wr = (wid >> 1) * 64, wc = (wid & 1) * 64;  // wave tile 64x64
  const int rl = lane >> 3, cl = lane & 7;              // staging row/chunk

  if (tid < 128) scw[tid] = (e == 16) ? 1.0f : cw[(size_t)(t0 + tid) * 16 + e];

  const __hip_bfloat16* wgE = wg + (size_t)e * FDIM * DDIM;
  const __hip_bfloat16* wuE = wu + (size_t)e * FDIM * DDIM;

  const f32x4 vzero = {0.f, 0.f, 0.f, 0.f};
  f32x4 accG[4][4], accU[4][4];
#pragma unroll
  for (int m = 0; m < 4; m++)
#pragma unroll
    for (int n = 0; n < 4; n++) { accG[m][n] = vzero; accU[m][n] = vzero; }

  for (int k0 = 0; k0 < DDIM; k0 += 64) {
    __syncthreads();  // previous iter's reads done before overwrite
    // stage: wave w loads rows [32w, 32w+32) of each tile; src chunk pre-swizzled
#pragma unroll
    for (int i = 0; i < 4; i++) {
      const int row = 32 * wid + 8 * i + rl;
      const int sw = (cl ^ (row & 7)) << 3;  // element offset of 16B chunk
      gload_lds16(xb  + (size_t)(t0 + row) * DDIM + k0 + sw, &sA[(32 * wid + 8 * i) * 64]);
      gload_lds16(wgE + (size_t)(f0 + row) * DDIM + k0 + sw, &sG[(32 * wid + 8 * i) * 64]);
      gload_lds16(wuE + (size_t)(f0 + row) * DDIM + k0 + sw, &sU[(32 * wid + 8 * i) * 64]);
    }
    __syncthreads();  // drains vmcnt -> staged data visible
#pragma unroll
    for (int kk = 0; kk < 2; kk++) {
      const int kch = kk * 4 + (lane >> 4);
      bf16x8 af[4], bg[4], bu[4];
#pragma unroll
      for (int m = 0; m < 4; m++) af[m] = frag_ld(sA, wr + m * 16 + (lane & 15), kch);
#pragma unroll
      for (int n = 0; n < 4; n++) {
        bg[n] = frag_ld(sG, wc + n * 16 + (lane & 15), kch);
        bu[n] = frag_ld(sU, wc + n * 16 + (lane & 15), kch);
      }
#pragma unroll
      for (int m = 0; m < 4; m++)
#pragma unroll
        for (int n = 0; n < 4; n++) {
          accG[m][n] = __builtin_amdgcn_mfma_f32_16x16x32_bf16(af[m], bg[n], accG[m][n], 0, 0, 0);
          accU[m][n] = __builtin_amdgcn_mfma_f32_16x16x32_bf16(af[m], bu[n], accU[m][n], 0, 0, 0);
        }
    }
  }
  // epilogue: h = silu(g)*u*cw -> bf16 H
  const int lr = (lane >> 4) * 4, lc = lane & 15;
#pragma unroll
  for (int m = 0; m < 4; m++)
#pragma unroll
    for (int n = 0; n < 4; n++)
#pragma unroll
      for (int j = 0; j < 4; j++) {
        const int r = wr + m * 16 + lr + j;
        const int c = wc + n * 16 + lc;
        const float g = accG[m][n][j], u = accU[m][n][j];
        const float h = (g / (1.0f + __expf(-g))) * u * scw[r];
        H[((size_t)e * T_TOK + t0 + r) * FDIM + f0 + c] = __float2bfloat16(h);
      }
}

// ---------------------------------------------------------------------------
// Stage B: out[t][d] = sum over K=17*512 (concat experts) of H[e][t][f] * Wd_t[e][d][f]
// Single fp32 accumulator per output element -> deterministic, no atomics.
__global__ __launch_bounds__(256, 2) void moe_stageB(
    const __hip_bfloat16* __restrict__ H,    // [17][T][F]
    const __hip_bfloat16* __restrict__ wd,   // [17][D][F]
    float* __restrict__ out)                 // [T][D]
{
  __shared__ __hip_bfloat16 sA[128 * 64];
  __shared__ __hip_bfloat16 sB[64 * 64];
  const int t0 = blockIdx.x * 128;
  const int d0 = blockIdx.y * 64;
  const int tid = threadIdx.x, wid = tid >> 6, lane = tid & 63;
  const int wr = (wid >> 1) * 64, wc = (wid & 1) * 32;  // wave tile 64x32
  const int rl = lane >> 3, cl = lane & 7;

  const f32x4 vzero = {0.f, 0.f, 0.f, 0.f};
  f32x4 acc[4][2];
#pragma unroll
  for (int m = 0; m < 4; m++)
#pragma unroll
    for (int n = 0; n < 2; n++) acc[m][n] = vzero;

  for (int k0 = 0; k0 < NE17 * FDIM; k0 += 64) {
    const int e = k0 >> 9, f = k0 & 511;  // FDIM=512 divisible by 64: no straddle
    __syncthreads();
#pragma unroll
    for (int i = 0; i < 4; i++) {
      const int row = 32 * wid + 8 * i + rl;
      const int sw = (cl ^ (row & 7)) << 3;
      gload_lds16(H + ((size_t)e * T_TOK + t0 + row) * FDIM + f + sw,
                  &sA[(32 * wid + 8 * i) * 64]);
    }
#pragma unroll
    for (int i = 0; i < 2; i++) {
      const int row = 16 * wid + 8 * i + rl;
      const int sw = (cl ^ (row & 7)) << 3;
      gload_lds16(wd + ((size_t)e * DDIM + d0 + row) * FDIM + f + sw,
                  &sB[(16 * wid + 8 * i) * 64]);
    }
    __syncthreads();
#pragma unroll
    for (int kk = 0; kk < 2; kk++) {
      const int kch = kk * 4 + (lane >> 4);
      bf16x8 af[4], bb[2];
#pragma unroll
      for (int m = 0; m < 4; m++) af[m] = frag_ld(sA, wr + m * 16 + (lane & 15), kch);
#pragma unroll
      for (int n = 0; n < 2; n++) bb[n] = frag_ld(sB, wc + n * 16 + (lane & 15), kch);
#pragma unroll
      for (int m = 0; m < 4; m++)
#pragma unroll
        for (int n = 0; n < 2; n++)
          acc[m][n] = __builtin_amdgcn_mfma_f32_16x16x32_bf16(af[m], bb[n], acc[m][n], 0, 0, 0);
    }
  }
  const int lr = (lane >> 4) * 4, lc = lane & 15;
#pragma unroll
  for (int m = 0; m < 4; m++)
#pragma unroll
    for (int n = 0; n < 2; n++)
#pragma unroll
      for (int j = 0; j < 4; j++)
        out[(size_t)(t0 + wr + m * 16 + lr + j) * DDIM + d0 + wc + n * 16 + lc] = acc[m][n][j];
}

// ---------------------------------------------------------------------------
extern "C" void kernel_launch(void* const* d_in, const int* in_sizes, int n_in,
                              void* d_out, int out_size, void* d_ws, size_t ws_size,
                              hipStream_t stream) {
  const float* x  = (const float*)d_in[0];  // [T][D]
  const float* rw = (const float*)d_in[1];  // [16][D]
  const float* gw = (const float*)d_in[2];  // [16][D][F]
  const float* uw = (const float*)d_in[3];  // [16][D][F]
  const float* dw = (const float*)d_in[4];  // [16][F][D]
  const float* sg = (const float*)d_in[5];  // [D][F]
  const float* su = (const float*)d_in[6];  // [D][F]
  const float* sd = (const float*)d_in[7];  // [F][D]
  float* out = (float*)d_out;
  // d_in[8] = top_k (hardcoded 8)

  // Workspace layout (needs ~127.3 MiB)
  char* ws = (char*)d_ws;
  size_t off = 0;
  __hip_bfloat16* xb = (__hip_bfloat16*)(ws + off); off += (size_t)T_TOK * DDIM * 2;
  __hip_bfloat16* wg = (__hip_bfloat16*)(ws + off); off += (size_t)NE17 * FDIM * DDIM * 2;
  __hip_bfloat16* wu = (__hip_bfloat16*)(ws + off); off += (size_t)NE17 * FDIM * DDIM * 2;
  __hip_bfloat16* wd = (__hip_bfloat16*)(ws + off); off += (size_t)NE17 * DDIM * FDIM * 2;
  __hip_bfloat16* H  = (__hip_bfloat16*)(ws + off); off += (size_t)NE17 * T_TOK * FDIM * 2;
  float* cw = (float*)(ws + off); off += (size_t)T_TOK * 16 * 4;
  (void)ws_size; (void)in_sizes; (void)n_in; (void)out_size;

  convert_bf16<<<(T_TOK * DDIM / 4 + 255) / 256, 256, 0, stream>>>(x, xb, T_TOK * DDIM / 4);
  dim3 tb(32, 8);
  // gate/up (+shared sg/su): [D][F] -> [F][D]
  transpose_convert<<<dim3(FDIM / 32, DDIM / 32, NE17), tb, 0, stream>>>(gw, sg, wg, DDIM, FDIM);
  transpose_convert<<<dim3(FDIM / 32, DDIM / 32, NE17), tb, 0, stream>>>(uw, su, wu, DDIM, FDIM);
  // down (+shared sd): [F][D] -> [D][F]
  transpose_convert<<<dim3(DDIM / 32, FDIM / 32, NE17), tb, 0, stream>>>(dw, sd, wd, FDIM, DDIM);
  moe_router<<<T_TOK, 64, 0, stream>>>(x, rw, cw);
  moe_stageA<<<dim3(T_TOK / 128, FDIM / 128, NE17), 256, 0, stream>>>(xb, wg, wu, cw, H);
  moe_stageB<<<dim3(T_TOK / 128, DDIM / 64), 256, 0, stream>>>(H, wd, out);
}